// Round 4
// baseline (7948.166 us; speedup 1.0000x reference)
//
#include <hip/hip_runtime.h>

typedef unsigned short ushort_t;
typedef unsigned int uint_t;

#define B_    16
#define L_    4096
#define H_    256
#define N_    32
#define DIN_  257
#define DOUT_ 257
#define NL_   4
#define Q_    128
#define NC_   32                 // L_/Q_
#define BL_   (B_*L_)            // 65536
#define NH_   (N_*H_)            // 8192
#define PLANE_ 16777216          // BL_*H_
#define SSZ_  4194304            // B_*NC_*N_*H_ (elements)

__device__ __forceinline__ float bfu(ushort_t u) {
    union { uint_t i; float f; } v; v.i = ((uint_t)u) << 16; return v.f;
}
__device__ __forceinline__ ushort_t f2bf(float f) {
    union { float f; uint_t i; } v; v.f = f;
    uint_t x = v.i;
    return (ushort_t)((x + 0x7FFFu + ((x >> 16) & 1u)) >> 16);
}
__device__ __forceinline__ uint2 pack4(float a, float b, float c, float d) {
    uint2 r;
    r.x = (uint_t)f2bf(a) | ((uint_t)f2bf(b) << 16);
    r.y = (uint_t)f2bf(c) | ((uint_t)f2bf(d) << 16);
    return r;
}
// dtype-flexible external-input load: f32!=0 -> fp32, else bf16
__device__ __forceinline__ float ldi(const void* p, size_t i, int f32) {
    return f32 ? ((const float*)p)[i] : bfu(((const ushort_t*)p)[i]);
}

// ---------------- dtype probe --------------------------------------------
// Low 16 bits of each 32-bit word: valid bf16 of N(0,1) if input is packed
// bf16 pairs; ~uniform random bits if input is fp32 (bottom mantissa).
__global__ void probe_kernel(const void* __restrict__ x, int* __restrict__ flag) {
    __shared__ int cnt;
    if (threadIdx.x == 0) cnt = 0;
    __syncthreads();
    uint_t w = ((const uint_t*)x)[threadIdx.x];
    float f = bfu((ushort_t)(w & 0xFFFF));
    float a = fabsf(f);
    if (a > 1e-5f && a < 100.f) atomicAdd(&cnt, 1);
    __syncthreads();
    if (threadIdx.x == 0) *flag = (cnt > 128) ? 0 : 1;  // 0 = bf16, 1 = fp32
}

// ---------------- SSM parameter precompute -------------------------------
// params layout per (layer,branch): [6][N][H]: wr, wi, ctr, cti, wqr, wqi
__global__ __launch_bounds__(256) void param_kernel(
        const void* __restrict__ log_dt, const void* __restrict__ lAr,
        const void* __restrict__ Aim, const void* __restrict__ C2,
        float* __restrict__ params, const int* __restrict__ dfl) {
    int f32 = *dfl;
    int idx = blockIdx.x * 256 + threadIdx.x;   // over NL_*2*N_*H_ = 65536
    int h  = idx & (H_ - 1);
    int n  = (idx >> 8) & (N_ - 1);
    int lb = idx >> 13;                          // layer*2+branch
    float dt = expf(ldi(log_dt, lb * H_ + h, f32));
    size_t pin = (size_t)(lb * H_ + h) * N_ + n;
    float Ar = -expf(ldi(lAr, pin, f32));
    float Ai = ldi(Aim, pin, f32);
    float Cr = ldi(C2, pin * 2, f32), Ci = ldi(C2, pin * 2 + 1, f32);
    float dr = Ar * dt, di = Ai * dt;
    float e  = expf(dr);
    float wr = e * cosf(di), wi = e * sinf(di);
    float Er = wr - 1.0f, Ei = wi;               // exp(dtA) - 1
    float inv = 1.0f / (Ar * Ar + Ai * Ai);
    float Fr = (Er * Ar + Ei * Ai) * inv;        // (exp(dtA)-1)/A
    float Fi = (Ei * Ar - Er * Ai) * inv;
    float ctr = 2.0f * (Cr * Fr - Ci * Fi);
    float cti = 2.0f * (Cr * Fi + Ci * Fr);
    float eq = expf((float)Q_ * dr);
    float ph = (float)Q_ * di;
    float wqr = eq * cosf(ph), wqi = eq * sinf(ph);
    float* pb = params + (size_t)lb * 6 * NH_;
    int o = n * H_ + h;
    pb[0 * NH_ + o] = wr;  pb[1 * NH_ + o] = wi;
    pb[2 * NH_ + o] = ctr; pb[3 * NH_ + o] = cti;
    pb[4 * NH_ + o] = wqr; pb[5 * NH_ + o] = wqi;
}

// ---------------- Encoder: complex GEMM (BL x 257) x (257 -> 256) --------
__global__ __launch_bounds__(256) void enc_gemm(
        const void* __restrict__ x, const void* __restrict__ Wr,
        const void* __restrict__ Wi, const void* __restrict__ br,
        const void* __restrict__ bi, ushort_t* __restrict__ xr,
        ushort_t* __restrict__ xi, const int* __restrict__ dfl) {
    __shared__ float Ar_s[16][64], Ai_s[16][64], Wr_s[16][64], Wi_s[16][64];
    int f32 = *dfl;
    int m0 = blockIdx.x * 64, n0 = blockIdx.y * 64;
    int tid = threadIdx.x;
    int ty = tid >> 4, tx = tid & 15;
    float accR[4][4] = {{0}}, accI[4][4] = {{0}};
    for (int k0 = 0; k0 < DIN_; k0 += 16) {
#pragma unroll
        for (int j = 0; j < 4; ++j) {            // A tile: 1024 (re,im) pairs
            int p = tid * 4 + j;
            int m = p >> 4, kk = p & 15;
            int k = k0 + kk;
            float r = 0.f, im = 0.f;
            if (k < DIN_) {
                size_t pi = (size_t)(m0 + m) * DIN_ + k;
                if (f32) {
                    float2 v = ((const float2*)x)[pi];
                    r = v.x; im = v.y;
                } else {
                    uint_t v = ((const uint_t*)x)[pi];
                    r  = bfu((ushort_t)(v & 0xFFFF));
                    im = bfu((ushort_t)(v >> 16));
                }
            }
            Ar_s[kk][m] = r; Ai_s[kk][m] = im;
        }
        {
            int n = tid >> 2, kpos = (tid & 3) * 4;
#pragma unroll
            for (int j = 0; j < 4; ++j) {
                int k = k0 + kpos + j;
                float wr_ = 0.f, wi_ = 0.f;
                if (k < DIN_) {
                    wr_ = ldi(Wr, (size_t)(n0 + n) * DIN_ + k, f32);
                    wi_ = ldi(Wi, (size_t)(n0 + n) * DIN_ + k, f32);
                }
                Wr_s[kpos + j][n] = wr_; Wi_s[kpos + j][n] = wi_;
            }
        }
        __syncthreads();
#pragma unroll
        for (int kk = 0; kk < 16; ++kk) {
            float ar[4], ai[4], ur[4], ui[4];
#pragma unroll
            for (int i = 0; i < 4; ++i) {
                ar[i] = Ar_s[kk][ty * 4 + i]; ai[i] = Ai_s[kk][ty * 4 + i];
                ur[i] = Wr_s[kk][tx * 4 + i]; ui[i] = Wi_s[kk][tx * 4 + i];
            }
#pragma unroll
            for (int i = 0; i < 4; ++i)
#pragma unroll
                for (int j = 0; j < 4; ++j) {
                    accR[i][j] = fmaf(ar[i], ur[j], fmaf(-ai[i], ui[j], accR[i][j]));
                    accI[i][j] = fmaf(ar[i], ui[j], fmaf( ai[i], ur[j], accI[i][j]));
                }
        }
        __syncthreads();
    }
    float bR[4], bI[4];
#pragma unroll
    for (int j = 0; j < 4; ++j) {
        bR[j] = ldi(br, n0 + tx * 4 + j, f32);
        bI[j] = ldi(bi, n0 + tx * 4 + j, f32);
    }
#pragma unroll
    for (int i = 0; i < 4; ++i) {
        size_t row = (size_t)(m0 + ty * 4 + i);
        size_t off = row * H_ + n0 + tx * 4;
        *(uint2*)(xr + off) = pack4(accR[i][0] + bR[0], accR[i][1] + bR[1],
                                    accR[i][2] + bR[2], accR[i][3] + bR[3]);
        *(uint2*)(xi + off) = pack4(accI[i][0] + bI[0], accI[i][1] + bI[1],
                                    accI[i][2] + bI[2], accI[i][3] + bI[3]);
    }
}

// ---------------- Pass A: per-chunk local state inject (states -> bf16) ---
__global__ __launch_bounds__(256) void pass_a(
        const ushort_t* __restrict__ U, const float* __restrict__ P, ushort_t* __restrict__ S) {
    int c = blockIdx.x, b = blockIdx.y, h = threadIdx.x;
    float wr[N_], wi[N_], sr[N_], si[N_];
#pragma unroll
    for (int n = 0; n < N_; ++n) {
        wr[n] = P[n * H_ + h]; wi[n] = P[NH_ + n * H_ + h];
        sr[n] = 0.f; si[n] = 0.f;
    }
    const ushort_t* u = U + (size_t)(b * L_ + c * Q_) * H_ + h;
    float uvn = bfu(u[0]);
    for (int t = 0; t < Q_; ++t) {
        float uv = uvn;
        int tn = (t + 1 < Q_) ? t + 1 : t;
        uvn = bfu(u[(size_t)tn * H_]);
#pragma unroll
        for (int n = 0; n < N_; ++n) {
            float nr = fmaf(wr[n], sr[n], fmaf(-wi[n], si[n], uv));
            si[n] = fmaf(wr[n], si[n], wi[n] * sr[n]);
            sr[n] = nr;
        }
    }
    size_t o = (size_t)(b * NC_ + c) * N_ * H_ + h;
#pragma unroll
    for (int n = 0; n < N_; ++n) {
        S[o + n * H_] = f2bf(sr[n]);
        S[o + n * H_ + SSZ_] = f2bf(si[n]);
    }
}

// ---------------- Pass B: chunk-level carry scan (in-place -> init state) -
__global__ __launch_bounds__(256) void pass_b(
        const float* __restrict__ P, ushort_t* __restrict__ S) {
    int n = blockIdx.x, b = blockIdx.y, h = threadIdx.x;
    float wqr = P[4 * NH_ + n * H_ + h], wqi = P[5 * NH_ + n * H_ + h];
    float Xr = 0.f, Xi = 0.f;
    for (int c = 0; c < NC_; ++c) {
        size_t idx = ((size_t)(b * NC_ + c) * N_ + n) * H_ + h;
        float lr = bfu(S[idx]), li = bfu(S[idx + SSZ_]);
        S[idx] = f2bf(Xr); S[idx + SSZ_] = f2bf(Xi);   // init state for chunk c
        float nr = fmaf(wqr, Xr, fmaf(-wqi, Xi, lr));
        Xi = fmaf(wqr, Xi, fmaf(wqi, Xr, li));
        Xr = nr;
    }
}

// ---------------- Pass C: scan w/ init + y=conv+D*u -> gelu --------------
// paired lanes: even/odd lane = low/high 16 states of same h
__global__ __launch_bounds__(256) void pass_c(
        const ushort_t* __restrict__ U, const float* __restrict__ P,
        const ushort_t* __restrict__ S, const void* __restrict__ Dp, int doff,
        ushort_t* __restrict__ G, const int* __restrict__ dfl) {
    int f32 = *dfl;
    int c = blockIdx.x, b = blockIdx.y;
    int tid = threadIdx.x;
    int h = blockIdx.z * 128 + (tid >> 1);
    int nb = (tid & 1) * 16;
    float wr[16], wi[16], cr[16], ci[16], sr[16], si[16];
#pragma unroll
    for (int i = 0; i < 16; ++i) {
        int o = (nb + i) * H_ + h;
        wr[i] = P[o]; wi[i] = P[NH_ + o];
        cr[i] = P[2 * NH_ + o]; ci[i] = P[3 * NH_ + o];
    }
    size_t so = (size_t)(b * NC_ + c) * N_ * H_ + h;
#pragma unroll
    for (int i = 0; i < 16; ++i) {
        sr[i] = bfu(S[so + (nb + i) * H_]);
        si[i] = bfu(S[so + (nb + i) * H_ + SSZ_]);
    }
    float Dv = ldi(Dp, (size_t)doff + h, f32);
    const ushort_t* u = U + (size_t)(b * L_ + c * Q_) * H_ + h;
    ushort_t* g = G + (size_t)(b * L_ + c * Q_) * H_ + h;
    float uvn = bfu(u[0]);
    for (int t = 0; t < Q_; ++t) {
        float uv = uvn;
        int tn = (t + 1 < Q_) ? t + 1 : t;
        uvn = bfu(u[(size_t)tn * H_]);
        float a0 = 0.f, a1 = 0.f;
#pragma unroll
        for (int i = 0; i < 16; ++i) {
            float nr = fmaf(wr[i], sr[i], fmaf(-wi[i], si[i], uv));
            si[i] = fmaf(wr[i], si[i], wi[i] * sr[i]);
            sr[i] = nr;
            if (i & 1) a1 = fmaf(cr[i], sr[i], fmaf(-ci[i], si[i], a1));
            else       a0 = fmaf(cr[i], sr[i], fmaf(-ci[i], si[i], a0));
        }
        float acc = a0 + a1;
        acc += __shfl_xor(acc, 1, 64);           // combine the two 16-state halves
        float y = fmaf(Dv, uv, acc);
        float ge = 0.5f * y * (1.0f + erff(y * 0.70710678118654752f));
        if ((tid & 1) == 0) g[(size_t)t * H_] = f2bf(ge);
    }
}

// ---------------- Wout GEMM + bias + GLU, accumulate into z --------------
// mode: 0 = store, 1 = add, 2 = sub
__global__ __launch_bounds__(256) void wout_gemm(
        const ushort_t* __restrict__ Gb, const void* __restrict__ W, size_t woff,
        const void* __restrict__ bo, int boff, ushort_t* __restrict__ Z, int mode,
        const int* __restrict__ dfl) {
    __shared__ float As[16][128], Wa_s[16][64], Wg_s[16][64];
    int f32 = *dfl;
    int m0 = blockIdx.x * 128, n0 = blockIdx.y * 64;
    int tid = threadIdx.x;
    int ty = tid >> 4, tx = tid & 15;
    float aa[8][4] = {{0}}, ag[8][4] = {{0}};
    for (int k0 = 0; k0 < H_; k0 += 16) {
        {   // A tile: 128 rows x 16 k, bf16 -> fp32 LDS
            int m = tid >> 1, kh = (tid & 1) * 8;
            uint4 v = *(const uint4*)(Gb + (size_t)(m0 + m) * H_ + k0 + kh);
            uint_t w[4] = {v.x, v.y, v.z, v.w};
#pragma unroll
            for (int j = 0; j < 4; ++j) {
                As[kh + 2 * j][m]     = bfu((ushort_t)(w[j] & 0xFFFF));
                As[kh + 2 * j + 1][m] = bfu((ushort_t)(w[j] >> 16));
            }
        }
        {
            int n = tid >> 2, kpos = (tid & 3) * 4;
            size_t ra = woff + (size_t)(n0 + n) * H_ + k0 + kpos;
            size_t rg = woff + (size_t)(256 + n0 + n) * H_ + k0 + kpos;
#pragma unroll
            for (int j = 0; j < 4; ++j) {
                Wa_s[kpos + j][n] = ldi(W, ra + j, f32);
                Wg_s[kpos + j][n] = ldi(W, rg + j, f32);
            }
        }
        __syncthreads();
#pragma unroll
        for (int kk = 0; kk < 16; ++kk) {
            float a[8], wa[4], wg[4];
#pragma unroll
            for (int i = 0; i < 8; ++i) a[i] = As[kk][ty * 8 + i];
#pragma unroll
            for (int j = 0; j < 4; ++j) { wa[j] = Wa_s[kk][tx * 4 + j]; wg[j] = Wg_s[kk][tx * 4 + j]; }
#pragma unroll
            for (int i = 0; i < 8; ++i)
#pragma unroll
                for (int j = 0; j < 4; ++j) {
                    aa[i][j] = fmaf(a[i], wa[j], aa[i][j]);
                    ag[i][j] = fmaf(a[i], wg[j], ag[i][j]);
                }
        }
        __syncthreads();
    }
    float ba[4], bg[4];
#pragma unroll
    for (int j = 0; j < 4; ++j) {
        ba[j] = ldi(bo, (size_t)boff + n0 + tx * 4 + j, f32);
        bg[j] = ldi(bo, (size_t)boff + 256 + n0 + tx * 4 + j, f32);
    }
#pragma unroll
    for (int i = 0; i < 8; ++i) {
        size_t ro = (size_t)(m0 + ty * 8 + i) * H_ + n0 + tx * 4;
        float s[4];
#pragma unroll
        for (int j = 0; j < 4; ++j) {
            float av = aa[i][j] + ba[j];
            float gv = ag[i][j] + bg[j];
            s[j] = av * (1.0f / (1.0f + expf(-gv)));
        }
        uint2* zp = (uint2*)(Z + ro);
        if (mode == 0) {
            *zp = pack4(s[0], s[1], s[2], s[3]);
        } else {
            uint2 ov = *zp;
            float o0 = bfu((ushort_t)(ov.x & 0xFFFF)), o1 = bfu((ushort_t)(ov.x >> 16));
            float o2 = bfu((ushort_t)(ov.y & 0xFFFF)), o3 = bfu((ushort_t)(ov.y >> 16));
            if (mode == 1) *zp = pack4(o0 + s[0], o1 + s[1], o2 + s[2], o3 + s[3]);
            else           *zp = pack4(o0 - s[0], o1 - s[1], o2 - s[2], o3 - s[3]);
        }
    }
}

// ---------------- residual + LayerNorm (both real & imag) ----------------
__global__ __launch_bounds__(256) void combine_ln(
        ushort_t* __restrict__ xr, ushort_t* __restrict__ xi,
        const ushort_t* __restrict__ zr, const ushort_t* __restrict__ zi,
        const void* __restrict__ gamma, const void* __restrict__ beta, int layer,
        const int* __restrict__ dfl) {
    __shared__ float red[4][4];
    int f32 = *dfl;
    int l = blockIdx.x, b = blockIdx.y, h = threadIdx.x;
    size_t row = (size_t)(b * L_ + l) * H_ + h;
    float vr = bfu(xr[row]) + bfu(zr[row]);
    float vi = bfu(xi[row]) + bfu(zi[row]);
    float s0 = vr, s1 = vr * vr, s2 = vi, s3 = vi * vi;
#pragma unroll
    for (int off = 32; off >= 1; off >>= 1) {
        s0 += __shfl_xor(s0, off, 64); s1 += __shfl_xor(s1, off, 64);
        s2 += __shfl_xor(s2, off, 64); s3 += __shfl_xor(s3, off, 64);
    }
    int wv = h >> 6;
    if ((h & 63) == 0) { red[wv][0] = s0; red[wv][1] = s1; red[wv][2] = s2; red[wv][3] = s3; }
    __syncthreads();
    float S0 = red[0][0] + red[1][0] + red[2][0] + red[3][0];
    float S1 = red[0][1] + red[1][1] + red[2][1] + red[3][1];
    float S2 = red[0][2] + red[1][2] + red[2][2] + red[3][2];
    float S3 = red[0][3] + red[1][3] + red[2][3] + red[3][3];
    const float invH = 1.0f / 256.0f;
    float mur = S0 * invH, varr = S1 * invH - mur * mur;
    float mui = S2 * invH, vari = S3 * invH - mui * mui;
    float gr = ldi(gamma, (size_t)(layer * 2 + 0) * H_ + h, f32);
    float br_ = ldi(beta, (size_t)(layer * 2 + 0) * H_ + h, f32);
    float gi = ldi(gamma, (size_t)(layer * 2 + 1) * H_ + h, f32);
    float bi_ = ldi(beta, (size_t)(layer * 2 + 1) * H_ + h, f32);
    xr[row] = f2bf((vr - mur) * rsqrtf(varr + 1e-5f) * gr + br_);
    xi[row] = f2bf((vi - mui) * rsqrtf(vari + 1e-5f) * gi + bi_);
}

// ---------------- Decoder: complex GEMM (BL x 256) x (256 -> 257) --------
__global__ __launch_bounds__(256) void dec_gemm(
        const ushort_t* __restrict__ xr, const ushort_t* __restrict__ xi,
        const void* __restrict__ Wr, const void* __restrict__ Wi,
        const void* __restrict__ br, const void* __restrict__ bi,
        void* __restrict__ out, const int* __restrict__ dfl) {
    __shared__ float Ar_s[16][64], Ai_s[16][64], Wr_s[16][64], Wi_s[16][64];
    int f32 = *dfl;
    int m0 = blockIdx.x * 64, n0 = blockIdx.y * 64;
    int tid = threadIdx.x, ty = tid >> 4, tx = tid & 15;
    float accR[4][4] = {{0}}, accI[4][4] = {{0}};
    for (int k0 = 0; k0 < H_; k0 += 16) {
        {
            int m = tid >> 2, kpos = (tid & 3) * 4;
            size_t off = (size_t)(m0 + m) * H_ + k0 + kpos;
            uint2 vr = *(const uint2*)(xr + off);
            uint2 vi = *(const uint2*)(xi + off);
            Ar_s[kpos][m]     = bfu((ushort_t)(vr.x & 0xFFFF));
            Ar_s[kpos + 1][m] = bfu((ushort_t)(vr.x >> 16));
            Ar_s[kpos + 2][m] = bfu((ushort_t)(vr.y & 0xFFFF));
            Ar_s[kpos + 3][m] = bfu((ushort_t)(vr.y >> 16));
            Ai_s[kpos][m]     = bfu((ushort_t)(vi.x & 0xFFFF));
            Ai_s[kpos + 1][m] = bfu((ushort_t)(vi.x >> 16));
            Ai_s[kpos + 2][m] = bfu((ushort_t)(vi.y & 0xFFFF));
            Ai_s[kpos + 3][m] = bfu((ushort_t)(vi.y >> 16));
        }
        {
            int n = tid >> 2, kpos = (tid & 3) * 4;
            int o = n0 + n;
#pragma unroll
            for (int j = 0; j < 4; ++j) {
                float wr_ = 0.f, wi_ = 0.f;
                if (o < DOUT_) {
                    wr_ = ldi(Wr, (size_t)o * H_ + k0 + kpos + j, f32);
                    wi_ = ldi(Wi, (size_t)o * H_ + k0 + kpos + j, f32);
                }
                Wr_s[kpos + j][n] = wr_; Wi_s[kpos + j][n] = wi_;
            }
        }
        __syncthreads();
#pragma unroll
        for (int kk = 0; kk < 16; ++kk) {
            float ar[4], ai[4], ur[4], ui[4];
#pragma unroll
            for (int i = 0; i < 4; ++i) {
                ar[i] = Ar_s[kk][ty * 4 + i]; ai[i] = Ai_s[kk][ty * 4 + i];
                ur[i] = Wr_s[kk][tx * 4 + i]; ui[i] = Wi_s[kk][tx * 4 + i];
            }
#pragma unroll
            for (int i = 0; i < 4; ++i)
#pragma unroll
                for (int j = 0; j < 4; ++j) {
                    accR[i][j] = fmaf(ar[i], ur[j], fmaf(-ai[i], ui[j], accR[i][j]));
                    accI[i][j] = fmaf(ar[i], ui[j], fmaf( ai[i], ur[j], accI[i][j]));
                }
        }
        __syncthreads();
    }
#pragma unroll
    for (int j = 0; j < 4; ++j) {
        int col = n0 + tx * 4 + j;
        if (col < DOUT_) {
            float bR = ldi(br, col, f32), bI = ldi(bi, col, f32);
#pragma unroll
            for (int i = 0; i < 4; ++i) {
                size_t row = (size_t)(m0 + ty * 4 + i);
                size_t pi = row * DOUT_ + col;
                float re = accR[i][j] + bR, im = accI[i][j] + bI;
                if (f32) {
                    ((float2*)out)[pi] = make_float2(re, im);
                } else {
                    uint_t pv = (uint_t)f2bf(re) | ((uint_t)f2bf(im) << 16);
                    ((uint_t*)out)[pi] = pv;
                }
            }
        }
    }
}

// -------------------------------------------------------------------------
extern "C" void kernel_launch(void* const* d_in, const int* in_sizes, int n_in,
                              void* d_out, int out_size, void* d_ws, size_t ws_size,
                              hipStream_t stream) {
    const void* x      = d_in[0];
    const void* enc_Wr = d_in[1];
    const void* enc_Wi = d_in[2];
    const void* enc_br = d_in[3];
    const void* enc_bi = d_in[4];
    const void* log_dt = d_in[5];
    const void* lAr    = d_in[6];
    const void* Aim    = d_in[7];
    const void* C2     = d_in[8];
    const void* Dp     = d_in[9];
    const void* Wout   = d_in[10];
    const void* bout   = d_in[11];
    const void* gamma  = d_in[12];
    const void* beta   = d_in[13];
    const void* dec_Wr = d_in[14];
    const void* dec_Wi = d_in[15];
    const void* dec_br = d_in[16];
    const void* dec_bi = d_in[17];

    // ws layout (~113.6 MiB):
    //   xr (32M) | xi (32M) | gb (32M) | st bf16 (16M) | flag | pr fp32 (1.5M)
    // zr/zi live in d_out (dead until dec_gemm rewrites every element last)
    ushort_t* xr = (ushort_t*)d_ws;
    ushort_t* xi = xr + (size_t)PLANE_;
    ushort_t* gb = xi + (size_t)PLANE_;
    ushort_t* st = gb + (size_t)PLANE_;
    int*      fl = (int*)(st + (size_t)2 * SSZ_);
    float*    pr = (float*)(fl + 64);            // 256-byte pad for alignment
    ushort_t* zr = (ushort_t*)d_out;
    ushort_t* zi = zr + (size_t)PLANE_;

    probe_kernel<<<1, 256, 0, stream>>>(x, fl);
    param_kernel<<<256, 256, 0, stream>>>(log_dt, lAr, Aim, C2, pr, fl);
    enc_gemm<<<dim3(BL_ / 64, H_ / 64), 256, 0, stream>>>(x, enc_Wr, enc_Wi, enc_br, enc_bi, xr, xi, fl);

    for (int l = 0; l < NL_; ++l) {
        // zr = sr(xr) - si(xi);  zi = sr(xi) + si(xr)
        struct App { int br; const ushort_t* U; ushort_t* Zt; int mode; };
        App apps[4] = {
            {0, xr, zr, 0},   // sr(xr) -> zr (store)
            {1, xi, zr, 2},   // si(xi) -> zr (sub)
            {0, xi, zi, 0},   // sr(xi) -> zi (store)
            {1, xr, zi, 1},   // si(xr) -> zi (add)
        };
        for (int a = 0; a < 4; ++a) {
            const float* P = pr + (size_t)(l * 2 + apps[a].br) * 6 * NH_;
            pass_a<<<dim3(NC_, B_), 256, 0, stream>>>(apps[a].U, P, st);
            pass_b<<<dim3(N_, B_), 256, 0, stream>>>(P, st);
            pass_c<<<dim3(NC_, B_, 2), 256, 0, stream>>>(apps[a].U, P, st,
                    Dp, (l * 2 + apps[a].br) * H_, gb, fl);
            wout_gemm<<<dim3(BL_ / 128, H_ / 64), 256, 0, stream>>>(gb,
                    Wout, (size_t)(l * 2 + apps[a].br) * 512 * H_,
                    bout, (l * 2 + apps[a].br) * 512,
                    apps[a].Zt, apps[a].mode, fl);
        }
        combine_ln<<<dim3(L_, B_), 256, 0, stream>>>(xr, xi, zr, zi, gamma, beta, l, fl);
    }

    dec_gemm<<<dim3(BL_ / 64, (DOUT_ + 63) / 64), 256, 0, stream>>>(
            xr, xi, dec_Wr, dec_Wi, dec_br, dec_bi, d_out, fl);
}